// Round 13
// baseline (39.403 us; speedup 1.0000x reference)
//
#include <hip/hip_runtime.h>
#include <hip/hip_fp16.h>
#include <math.h>

typedef _Float16 f16x8 __attribute__((ext_vector_type(8)));
typedef float f32x4 __attribute__((ext_vector_type(4)));

#define NS 4
#define HID 512
#define IN_DIM 342
#define OUT_DIM 311
#define BATCH 1024
#define INP 352            // IN_DIM padded to mult of 32
#define K0V (NS*INP)       // 1408
#define K12V (NS*HID)      // 2048
#define XROW (IN_DIM+1)    // 343

// workspace float offsets (~11.9 MB)
#define OFF_ACOEF 0
#define OFF_X0H   4096
#define OFF_W0H   (OFF_X0H + 720896)
#define OFF_W1H   (OFF_W0H + 360448)
#define OFF_W2H   (OFF_W1H + 524288)
#define OFF_H1X   (OFF_W2H + 327680)
#define OFF_H2X   OFF_X0H      // overlays X0h+part of W0h (dead after L0)

typedef __attribute__((address_space(3))) void lds_t;
typedef __attribute__((address_space(1))) const void gvm_t;
__device__ __forceinline__ void gload16(const void* g, void* l) {
    __builtin_amdgcn_global_load_lds((gvm_t*)g, (lds_t*)l, 16, 0, 0);
}

// ---- prep: X0h + W0h only (f16x8-vectorized stores) ----
// blocks [0,512):   W0h row o   (176 chunks of 8)
// blocks [512,1536): X0h row b + acoef[b]
__global__ __launch_bounds__(256) void prep_xw0(
    const float* __restrict__ x,
    const float* __restrict__ W0,
    float* __restrict__ acoef,
    __half* __restrict__ X0h, __half* __restrict__ W0h)
{
    const int bid = blockIdx.x;
    const int t = threadIdx.x;
    if (bid < 512) {                       // W0h row o
        int o = bid;
        if (t < 176) {
            int s = t / 44;
            int cm = t - s*44;
            int i = cm * 8;
            const float* src = W0 + ((size_t)s*HID + o)*IN_DIM + i;
            f16x8 h;
            if (i + 8 <= IN_DIM) {
                float4 v0 = *(const float4*)(src);
                float4 v1 = *(const float4*)(src + 4);
                h[0]=(_Float16)v0.x; h[1]=(_Float16)v0.y; h[2]=(_Float16)v0.z; h[3]=(_Float16)v0.w;
                h[4]=(_Float16)v1.x; h[5]=(_Float16)v1.y; h[6]=(_Float16)v1.z; h[7]=(_Float16)v1.w;
            } else {
                #pragma unroll
                for (int j=0;j<8;++j) h[j] = (_Float16)((i+j < IN_DIM) ? src[j] : 0.f);
            }
            *(f16x8*)(W0h + (size_t)o*K0V + t*8) = h;
        }
    } else {                               // X0h row b + acoef
        int b = bid - 512;
        float phase = x[(size_t)b*XROW + IN_DIM];
        float ps = (float)NS * phase;
        float mu = ps - floorf(ps);
        int i1 = ((int)ps) & (NS-1);
        float mu2 = mu*mu, mu3 = mu2*mu;
        float r0 =  1.5f*mu3 - 2.5f*mu2 + 1.0f;        // rel 0
        float r1 = -1.5f*mu3 + 2.0f*mu2 + 0.5f*mu;     // rel 1
        float r2 =  0.5f*mu3 - 0.5f*mu2;               // rel 2
        float r3 = -0.5f*mu3 +      mu2 - 0.5f*mu;     // rel 3
        if (t < 4) {
            int rel = (t - i1) & 3;
            acoef[b*4 + t] = (rel==0)?r0:(rel==1)?r1:(rel==2)?r2:r3;
        }
        if (t < 176) {
            int s = t / 44;
            int cm = t - s*44;
            int i = cm * 8;
            int rel = (s - i1) & 3;
            float sc = (rel==0)?r0:(rel==1)?r1:(rel==2)?r2:r3;
            const float* src = x + (size_t)b*XROW + i;
            f16x8 h;
            if (i + 8 <= IN_DIM) {
                float4 v0 = *(const float4*)(src);
                float4 v1 = *(const float4*)(src + 4);
                h[0]=(_Float16)(v0.x*sc); h[1]=(_Float16)(v0.y*sc);
                h[2]=(_Float16)(v0.z*sc); h[3]=(_Float16)(v0.w*sc);
                h[4]=(_Float16)(v1.x*sc); h[5]=(_Float16)(v1.y*sc);
                h[6]=(_Float16)(v1.z*sc); h[7]=(_Float16)(v1.w*sc);
            } else {
                #pragma unroll
                for (int j=0;j<8;++j) h[j] = (_Float16)((i+j < IN_DIM) ? src[j]*sc : 0.f);
            }
            *(f16x8*)(X0h + (size_t)b*K0V + t*8) = h;
        }
    }
}

// ---- MFMA GEMM: BM=32 x BN=64, BK=128, 256 thr (4 waves), acc[2] ----
// gload_lds staging into a 4-slot LDS ring (24KB/slot), depth-3 prefetch,
// counted vmcnt (6 loads/wave/slot -> 12/6/0). LDS dest linear; global
// source pre-swizzled; ds_reads XOR the same bits (involution).
// LAYER 0: 1D grid; bid<256 GEMM (m=bid>>3, n=bid&7); bid>=256 repack
//          W1h/W2h (no LDS -> co-schedules in free wave slots).
template<int LAYER>
__global__ __launch_bounds__(256) void gemm_mfma(
    const __half* __restrict__ A,
    const __half* __restrict__ Bw,
    const float* __restrict__ acoef,
    const float* __restrict__ bias,
    __half* __restrict__ outH,
    float* __restrict__ outF,
    const float* __restrict__ W1f, const float* __restrict__ W2f,
    __half* __restrict__ W1h, __half* __restrict__ W2h)
{
    constexpr int K  = (LAYER==0) ? K0V : K12V;
    constexpr int NB = (LAYER==2) ? OUT_DIM : HID;
    constexpr int NITER = K / 128;          // 11 / 16 / 16

    const int t = threadIdx.x;

    if (LAYER == 0 && blockIdx.x >= 256) {   // ---- W1/W2 repack (no LDS) ----
        int j = blockIdx.x - 256;             // 0..415
        int half = t >> 7;                    // 2 rows per block
        int tt = t & 127;                     // 16 f16 per thread
        int k = tt * 16;
        int s = k >> 9, i = k & 511;
        f16x8 h0 = {}, h1 = {};
        __half* dst;
        if (j < 256) {                        // W1: o = 0..511
            int o = j*2 + half;
            const float* src = W1f + ((size_t)s*HID + o)*HID + i;
            float4 v0 = *(const float4*)(src);
            float4 v1 = *(const float4*)(src + 4);
            float4 v2 = *(const float4*)(src + 8);
            float4 v3 = *(const float4*)(src + 12);
            h0[0]=(_Float16)v0.x; h0[1]=(_Float16)v0.y; h0[2]=(_Float16)v0.z; h0[3]=(_Float16)v0.w;
            h0[4]=(_Float16)v1.x; h0[5]=(_Float16)v1.y; h0[6]=(_Float16)v1.z; h0[7]=(_Float16)v1.w;
            h1[0]=(_Float16)v2.x; h1[1]=(_Float16)v2.y; h1[2]=(_Float16)v2.z; h1[3]=(_Float16)v2.w;
            h1[4]=(_Float16)v3.x; h1[5]=(_Float16)v3.y; h1[6]=(_Float16)v3.z; h1[7]=(_Float16)v3.w;
            dst = W1h + (size_t)o*K12V + k;
        } else {                              // W2: o = 0..319 (>=311 zero)
            int o = (j-256)*2 + half;
            if (o < OUT_DIM) {
                const float* src = W2f + ((size_t)s*OUT_DIM + o)*HID + i;
                float4 v0 = *(const float4*)(src);
                float4 v1 = *(const float4*)(src + 4);
                float4 v2 = *(const float4*)(src + 8);
                float4 v3 = *(const float4*)(src + 12);
                h0[0]=(_Float16)v0.x; h0[1]=(_Float16)v0.y; h0[2]=(_Float16)v0.z; h0[3]=(_Float16)v0.w;
                h0[4]=(_Float16)v1.x; h0[5]=(_Float16)v1.y; h0[6]=(_Float16)v1.z; h0[7]=(_Float16)v1.w;
                h1[0]=(_Float16)v2.x; h1[1]=(_Float16)v2.y; h1[2]=(_Float16)v2.z; h1[3]=(_Float16)v2.w;
                h1[4]=(_Float16)v3.x; h1[5]=(_Float16)v3.y; h1[6]=(_Float16)v3.z; h1[7]=(_Float16)v3.w;
            }
            dst = W2h + (size_t)o*K12V + k;
        }
        *(f16x8*)(dst)     = h0;
        *(f16x8*)(dst + 8) = h1;
        return;
    }

    // ---------------- GEMM ----------------
    __shared__ __align__(16) char lbuf[4][24576];   // A 8KB | B 16KB per slot

    const int lane = t & 63;
    const int wid  = t >> 6;
    const int wm   = wid >> 1;
    const int wn   = wid & 1;
    const int m0   = (LAYER==0) ? (blockIdx.x >> 3)*32 : blockIdx.y * 32;
    const int n0   = (LAYER==0) ? (blockIdx.x & 7)*64  : blockIdx.x * 64;

    // per-lane staging source addresses (pre-swizzled global chunks)
    const int cS = lane & 15;               // lds 16B-chunk within row
    const int r4 = lane >> 4;               // row within 1KB gload chunk
    const int rA0 = 4*(wid    ) + r4;
    const int rA1 = 4*(wid + 4) + r4;
    const __half* aSrc0 = A + (size_t)(m0 + rA0)*K + (((cS&8)|((cS&7)^(rA0&7))) * 8);
    const __half* aSrc1 = A + (size_t)(m0 + rA1)*K + (((cS&8)|((cS&7)^(rA1&7))) * 8);
    const int rB0 = 4*(wid     ) + r4;
    const int rB1 = 4*(wid +  4) + r4;
    const int rB2 = 4*(wid +  8) + r4;
    const int rB3 = 4*(wid + 12) + r4;
    const __half* bSrc0 = Bw + (size_t)(n0 + rB0)*K + (((cS&8)|((cS&7)^(rB0&7))) * 8);
    const __half* bSrc1 = Bw + (size_t)(n0 + rB1)*K + (((cS&8)|((cS&7)^(rB1&7))) * 8);
    const __half* bSrc2 = Bw + (size_t)(n0 + rB2)*K + (((cS&8)|((cS&7)^(rB2&7))) * 8);
    const __half* bSrc3 = Bw + (size_t)(n0 + rB3)*K + (((cS&8)|((cS&7)^(rB3&7))) * 8);

    f32x4 acc[2] = {};

    auto stage = [&](int it) {
        char* base = lbuf[it & 3];
        const int ko = it * 128;
        gload16(aSrc0 + ko, base + (wid    )*1024);
        gload16(aSrc1 + ko, base + (wid + 4)*1024);
        gload16(bSrc0 + ko, base + 8192 + (wid     )*1024);
        gload16(bSrc1 + ko, base + 8192 + (wid +  4)*1024);
        gload16(bSrc2 + ko, base + 8192 + (wid +  8)*1024);
        gload16(bSrc3 + ko, base + 8192 + (wid + 12)*1024);
    };

    stage(0);
    stage(1);
    stage(2);

    for (int it = 0; it < NITER; ++it) {
        if (it + 2 < NITER)      asm volatile("s_waitcnt vmcnt(12)" ::: "memory");
        else if (it + 1 < NITER) asm volatile("s_waitcnt vmcnt(6)"  ::: "memory");
        else                     asm volatile("s_waitcnt vmcnt(0)"  ::: "memory");
        __builtin_amdgcn_s_barrier();
        __builtin_amdgcn_sched_barrier(0);
        if (it + 3 < NITER) stage(it + 3);
        const char* sA = lbuf[it & 3];
        const char* sB = sA + 8192;
        #pragma unroll
        for (int kk = 0; kk < 4; ++kk) {
            const int kb = kk*64 + (lane>>4)*16;
            const int rr = wm*16 + (lane&15);
            f16x8 af = *(const f16x8*)(sA + rr*256 + (kb ^ ((rr&7)<<4)));
            #pragma unroll
            for (int ni = 0; ni < 2; ++ni) {
                const int oo = wn*32 + ni*16 + (lane&15);
                f16x8 bf = *(const f16x8*)(sB + oo*256 + (kb ^ ((oo&7)<<4)));
                acc[ni] = __builtin_amdgcn_mfma_f32_16x16x32_f16(af, bf, acc[ni], 0, 0, 0);
            }
        }
    }

    // ---- epilogue: D layout col=lane&15, row=(lane>>4)*4+r ----
    #pragma unroll
    for (int r = 0; r < 4; ++r) {
        const int row = m0 + wm*16 + (lane>>4)*4 + r;
        const float c0 = acoef[row*4+0], c1 = acoef[row*4+1],
                    c2 = acoef[row*4+2], c3 = acoef[row*4+3];
        #pragma unroll
        for (int ni = 0; ni < 2; ++ni) {
            const int col = n0 + wn*32 + ni*16 + (lane&15);
            float v = acc[ni][r];
            if (LAYER == 2) {
                if (col < OUT_DIM) {
                    float bi = c0*bias[col] + c1*bias[NB+col]
                             + c2*bias[2*NB+col] + c3*bias[3*NB+col];
                    outF[(size_t)row*OUT_DIM + col] = v + bi;
                }
            } else {
                float bi = c0*bias[col] + c1*bias[NB+col]
                         + c2*bias[2*NB+col] + c3*bias[3*NB+col];
                v += bi;
                v = (v > 0.f) ? v : expm1f(v);
                size_t o = (size_t)row*K12V + col;
                outH[o        ] = __float2half(c0*v);
                outH[o +   HID] = __float2half(c1*v);
                outH[o + 2*HID] = __float2half(c2*v);
                outH[o + 3*HID] = __float2half(c3*v);
            }
        }
    }
}

extern "C" void kernel_launch(void* const* d_in, const int* in_sizes, int n_in,
                              void* d_out, int out_size, void* d_ws, size_t ws_size,
                              hipStream_t stream) {
    const float* x  = (const float*)d_in[0];
    const float* W0 = (const float*)d_in[1];
    const float* W1 = (const float*)d_in[2];
    const float* W2 = (const float*)d_in[3];
    const float* b0 = (const float*)d_in[4];
    const float* b1 = (const float*)d_in[5];
    const float* b2 = (const float*)d_in[6];
    float* out = (float*)d_out;
    float* ws  = (float*)d_ws;

    float*  acoef = ws + OFF_ACOEF;
    __half* X0h   = (__half*)(ws + OFF_X0H);
    __half* W0h   = (__half*)(ws + OFF_W0H);
    __half* W1h   = (__half*)(ws + OFF_W1H);
    __half* W2h   = (__half*)(ws + OFF_W2H);
    __half* H1x   = (__half*)(ws + OFF_H1X);
    __half* H2x   = (__half*)(ws + OFF_H2X);

    prep_xw0<<<dim3(1536), dim3(256), 0, stream>>>(x, W0, acoef, X0h, W0h);

    // L0 GEMM (256 blocks) + W1/W2 repack (416 LDS-free blocks, co-resident)
    gemm_mfma<0><<<dim3(672), dim3(256), 0, stream>>>(
        X0h, W0h, acoef, b0, H1x, nullptr, W1, W2, W1h, W2h);
    gemm_mfma<1><<<dim3(HID/64, BATCH/32), dim3(256), 0, stream>>>(
        H1x, W1h, acoef, b1, H2x, nullptr, nullptr, nullptr, nullptr, nullptr);
    gemm_mfma<2><<<dim3(320/64, BATCH/32), dim3(256), 0, stream>>>(
        H2x, W2h, acoef, b2, nullptr, out, nullptr, nullptr, nullptr, nullptr);
}

// Round 14
// 38.532 us; speedup vs baseline: 1.0226x; 1.0226x over previous
//
#include <hip/hip_runtime.h>
#include <hip/hip_fp16.h>
#include <math.h>

typedef _Float16 f16x8 __attribute__((ext_vector_type(8)));
typedef float f32x4 __attribute__((ext_vector_type(4)));

#define NS 4
#define HID 512
#define IN_DIM 342
#define OUT_DIM 311
#define BATCH 1024
#define INP 352            // IN_DIM padded to mult of 32
#define K0V (NS*INP)       // 1408
#define K12V (NS*HID)      // 2048
#define XROW (IN_DIM+1)    // 343

// workspace float offsets (~11.9 MB)
#define OFF_ACOEF 0
#define OFF_X0H   4096
#define OFF_W0H   (OFF_X0H + 720896)
#define OFF_W1H   (OFF_W0H + 360448)
#define OFF_W2H   (OFF_W1H + 524288)
#define OFF_H1X   (OFF_W2H + 327680)
#define OFF_H2X   OFF_X0H      // overlays X0h+part of W0h (dead after L0)

typedef __attribute__((address_space(3))) void lds_t;
typedef __attribute__((address_space(1))) const void gvm_t;
__device__ __forceinline__ void gload16(const void* g, void* l) {
    __builtin_amdgcn_global_load_lds((gvm_t*)g, (lds_t*)l, 16, 0, 0);
}

// ---- fused prep kernel (R4/R12-proven) ----
__global__ __launch_bounds__(256) void prep_all(
    const float* __restrict__ x,
    const float* __restrict__ W0, const float* __restrict__ W1,
    const float* __restrict__ W2,
    float* __restrict__ acoef,
    __half* __restrict__ X0h, __half* __restrict__ W0h,
    __half* __restrict__ W1h, __half* __restrict__ W2h)
{
    const int bid = blockIdx.x;
    const int t = threadIdx.x;
    if (bid < 512) {                       // W0h
        int o = bid;
        for (int k = t; k < K0V; k += 256) {
            int s = k / INP;
            int i = k - s*INP;
            float v = 0.f;
            if (i < IN_DIM) v = W0[((size_t)s*HID + o)*IN_DIM + i];
            W0h[(size_t)o*K0V + k] = __float2half(v);
        }
    } else if (bid < 1024) {               // W1h
        int o = bid - 512;
        int k = t * 8;
        int s = k >> 9, i = k & 511;
        const float* src = W1 + ((size_t)s*HID + o)*HID + i;
        float4 v0 = *(const float4*)(src);
        float4 v1 = *(const float4*)(src + 4);
        f16x8 h;
        h[0]=(_Float16)v0.x; h[1]=(_Float16)v0.y; h[2]=(_Float16)v0.z; h[3]=(_Float16)v0.w;
        h[4]=(_Float16)v1.x; h[5]=(_Float16)v1.y; h[6]=(_Float16)v1.z; h[7]=(_Float16)v1.w;
        *(f16x8*)(W1h + (size_t)o*K12V + k) = h;
    } else if (bid < 1344) {               // W2h
        int o = bid - 1024;                 // 0..319
        int k = t * 8;
        int s = k >> 9, i = k & 511;
        f16x8 h = {};
        if (o < OUT_DIM) {
            const float* src = W2 + ((size_t)s*OUT_DIM + o)*HID + i;
            float4 v0 = *(const float4*)(src);
            float4 v1 = *(const float4*)(src + 4);
            h[0]=(_Float16)v0.x; h[1]=(_Float16)v0.y; h[2]=(_Float16)v0.z; h[3]=(_Float16)v0.w;
            h[4]=(_Float16)v1.x; h[5]=(_Float16)v1.y; h[6]=(_Float16)v1.z; h[7]=(_Float16)v1.w;
        }
        *(f16x8*)(W2h + (size_t)o*K12V + k) = h;
    } else {                               // X0h + acoef
        int b = bid - 1344;
        float phase = x[(size_t)b*XROW + IN_DIM];
        float ps = (float)NS * phase;
        float mu = ps - floorf(ps);
        int i1 = ((int)ps) & (NS-1);
        float mu2 = mu*mu, mu3 = mu2*mu;
        float c1 =  1.5f*mu3 - 2.5f*mu2 + 1.0f;        // rel 0
        float c2 = -1.5f*mu3 + 2.0f*mu2 + 0.5f*mu;     // rel 1
        float c3 =  0.5f*mu3 - 0.5f*mu2;               // rel 2
        float c0 = -0.5f*mu3 +      mu2 - 0.5f*mu;     // rel 3
        if (t < 4) {
            int rel = (t - i1) & 3;
            acoef[b*4 + t] = (rel==0)?c1:(rel==1)?c2:(rel==2)?c3:c0;
        }
        for (int k = t; k < K0V; k += 256) {
            int s = k / INP;
            int i = k - s*INP;
            int rel = (s - i1) & 3;
            float sel = (rel==0)?c1:(rel==1)?c2:(rel==2)?c3:c0;
            float v = (i < IN_DIM) ? x[(size_t)b*XROW + i] * sel : 0.f;
            X0h[(size_t)b*K0V + k] = __float2half(v);
        }
    }
}

// ---- MFMA GEMM: BM=32 x BN=64, BK=128, 256 thr (4 waves), acc[2] ----
// gload_lds into a 4-slot LDS ring (24KB/slot), depth-3 prefetch, counted
// vmcnt (12/6/0). LDS dest linear; global source pre-swizzled; ds_reads
// XOR the same bits (involution).
// NEW (R14): XCD-aware tile mapping — xcd = bid&7 owns a contiguous
// rectangle (8m x 4n for L0/L1; 4m x 5n for L2) so per-XCD L2 footprint
// drops from ~4.3MB to ~2MB (T1).
template<int LAYER>
__global__ __launch_bounds__(256) void gemm_mfma(
    const __half* __restrict__ A,
    const __half* __restrict__ Bw,
    const float* __restrict__ acoef,
    const float* __restrict__ bias,
    __half* __restrict__ outH,
    float* __restrict__ outF)
{
    constexpr int K  = (LAYER==0) ? K0V : K12V;
    constexpr int NB = (LAYER==2) ? OUT_DIM : HID;
    constexpr int NITER = K / 128;          // 11 / 16 / 16

    __shared__ __align__(16) char lbuf[4][24576];   // A 8KB | B 16KB per slot

    const int t    = threadIdx.x;
    const int lane = t & 63;
    const int wid  = t >> 6;
    const int wm   = wid >> 1;
    const int wn   = wid & 1;

    // XCD-aware rectangular tile mapping (assumes bid%8 -> XCD round-robin;
    // perf heuristic only, any mapping is correct)
    const int bid = blockIdx.x;
    const int xcd = bid & 7;
    const int j   = bid >> 3;
    int m0, n0;
    if (LAYER == 2) {              // 32 m-tiles x 5 n-tiles, 160 blocks
        m0 = (xcd*4 + (j & 3)) * 32;
        n0 = (j >> 2) * 64;
    } else {                       // 32 m-tiles x 8 n-tiles, 256 blocks
        const int mg = xcd >> 1, ng = xcd & 1;
        m0 = (mg*8 + (j & 7)) * 32;
        n0 = (ng*4 + (j >> 3)) * 64;
    }

    // per-lane staging source addresses (pre-swizzled global chunks)
    const int cS = lane & 15;               // lds 16B-chunk within row
    const int r4 = lane >> 4;               // row within 1KB gload chunk
    const int rA0 = 4*(wid    ) + r4;
    const int rA1 = 4*(wid + 4) + r4;
    const __half* aSrc0 = A + (size_t)(m0 + rA0)*K + (((cS&8)|((cS&7)^(rA0&7))) * 8);
    const __half* aSrc1 = A + (size_t)(m0 + rA1)*K + (((cS&8)|((cS&7)^(rA1&7))) * 8);
    const int rB0 = 4*(wid     ) + r4;
    const int rB1 = 4*(wid +  4) + r4;
    const int rB2 = 4*(wid +  8) + r4;
    const int rB3 = 4*(wid + 12) + r4;
    const __half* bSrc0 = Bw + (size_t)(n0 + rB0)*K + (((cS&8)|((cS&7)^(rB0&7))) * 8);
    const __half* bSrc1 = Bw + (size_t)(n0 + rB1)*K + (((cS&8)|((cS&7)^(rB1&7))) * 8);
    const __half* bSrc2 = Bw + (size_t)(n0 + rB2)*K + (((cS&8)|((cS&7)^(rB2&7))) * 8);
    const __half* bSrc3 = Bw + (size_t)(n0 + rB3)*K + (((cS&8)|((cS&7)^(rB3&7))) * 8);

    f32x4 acc[2] = {};

    auto stage = [&](int it) {
        char* base = lbuf[it & 3];
        const int ko = it * 128;
        gload16(aSrc0 + ko, base + (wid    )*1024);
        gload16(aSrc1 + ko, base + (wid + 4)*1024);
        gload16(bSrc0 + ko, base + 8192 + (wid     )*1024);
        gload16(bSrc1 + ko, base + 8192 + (wid +  4)*1024);
        gload16(bSrc2 + ko, base + 8192 + (wid +  8)*1024);
        gload16(bSrc3 + ko, base + 8192 + (wid + 12)*1024);
    };

    stage(0);
    stage(1);
    stage(2);

    for (int it = 0; it < NITER; ++it) {
        if (it + 2 < NITER)      asm volatile("s_waitcnt vmcnt(12)" ::: "memory");
        else if (it + 1 < NITER) asm volatile("s_waitcnt vmcnt(6)"  ::: "memory");
        else                     asm volatile("s_waitcnt vmcnt(0)"  ::: "memory");
        __builtin_amdgcn_s_barrier();
        __builtin_amdgcn_sched_barrier(0);
        if (it + 3 < NITER) stage(it + 3);
        const char* sA = lbuf[it & 3];
        const char* sB = sA + 8192;
        #pragma unroll
        for (int kk = 0; kk < 4; ++kk) {
            const int kb = kk*64 + (lane>>4)*16;
            const int rr = wm*16 + (lane&15);
            f16x8 af = *(const f16x8*)(sA + rr*256 + (kb ^ ((rr&7)<<4)));
            #pragma unroll
            for (int ni = 0; ni < 2; ++ni) {
                const int oo = wn*32 + ni*16 + (lane&15);
                f16x8 bf = *(const f16x8*)(sB + oo*256 + (kb ^ ((oo&7)<<4)));
                acc[ni] = __builtin_amdgcn_mfma_f32_16x16x32_f16(af, bf, acc[ni], 0, 0, 0);
            }
        }
    }

    // ---- epilogue (proven): D layout col=lane&15, row=(lane>>4)*4+r ----
    #pragma unroll
    for (int r = 0; r < 4; ++r) {
        const int row = m0 + wm*16 + (lane>>4)*4 + r;
        const float c0 = acoef[row*4+0], c1 = acoef[row*4+1],
                    c2 = acoef[row*4+2], c3 = acoef[row*4+3];
        #pragma unroll
        for (int ni = 0; ni < 2; ++ni) {
            const int col = n0 + wn*32 + ni*16 + (lane&15);
            float v = acc[ni][r];
            if (LAYER == 2) {
                if (col < OUT_DIM) {
                    float bi = c0*bias[col] + c1*bias[NB+col]
                             + c2*bias[2*NB+col] + c3*bias[3*NB+col];
                    outF[(size_t)row*OUT_DIM + col] = v + bi;
                }
            } else {
                float bi = c0*bias[col] + c1*bias[NB+col]
                         + c2*bias[2*NB+col] + c3*bias[3*NB+col];
                v += bi;
                v = (v > 0.f) ? v : expm1f(v);
                size_t o = (size_t)row*K12V + col;
                outH[o        ] = __float2half(c0*v);
                outH[o +   HID] = __float2half(c1*v);
                outH[o + 2*HID] = __float2half(c2*v);
                outH[o + 3*HID] = __float2half(c3*v);
            }
        }
    }
}

extern "C" void kernel_launch(void* const* d_in, const int* in_sizes, int n_in,
                              void* d_out, int out_size, void* d_ws, size_t ws_size,
                              hipStream_t stream) {
    const float* x  = (const float*)d_in[0];
    const float* W0 = (const float*)d_in[1];
    const float* W1 = (const float*)d_in[2];
    const float* W2 = (const float*)d_in[3];
    const float* b0 = (const float*)d_in[4];
    const float* b1 = (const float*)d_in[5];
    const float* b2 = (const float*)d_in[6];
    float* out = (float*)d_out;
    float* ws  = (float*)d_ws;

    float*  acoef = ws + OFF_ACOEF;
    __half* X0h   = (__half*)(ws + OFF_X0H);
    __half* W0h   = (__half*)(ws + OFF_W0H);
    __half* W1h   = (__half*)(ws + OFF_W1H);
    __half* W2h   = (__half*)(ws + OFF_W2H);
    __half* H1x   = (__half*)(ws + OFF_H1X);
    __half* H2x   = (__half*)(ws + OFF_H2X);

    prep_all<<<dim3(2368), dim3(256), 0, stream>>>(x, W0, W1, W2, acoef,
                                                   X0h, W0h, W1h, W2h);

    gemm_mfma<0><<<dim3(256), dim3(256), 0, stream>>>(
        X0h, W0h, acoef, b0, H1x, nullptr);
    gemm_mfma<1><<<dim3(256), dim3(256), 0, stream>>>(
        H1x, W1h, acoef, b1, H2x, nullptr);
    gemm_mfma<2><<<dim3(160), dim3(256), 0, stream>>>(
        H2x, W2h, acoef, b2, nullptr, out);
}